// Round 2
// baseline (367.231 us; speedup 1.0000x reference)
//
#include <hip/hip_runtime.h>
#include <math.h>

#define SQ 2048      // seq len
#define DE 512       // d_embedding
#define DH 64        // d_head
#define CW 128       // half-window
#define W2 256       // window width
#define NH 8         // heads
#define NQ 4         // queries per block
#define UW (W2 + NQ - 1)  // union window width = 259
#define NT 512       // threads per block
#define NW 8         // waves per block

// Broadcast small shared operands via v_readlane (VALU/SGPR path) instead of
// uniform-address LDS reads (which serialize on the single per-CU LDS pipe).
// HAZARD: readlane sources must be defined in ALL 64 lanes -> every readlane
// use site must be reached with a full exec mask (wave-uniform branches only).
__device__ __forceinline__ float rl(float x, int l) {
  return __int_as_float(__builtin_amdgcn_readlane(__float_as_int(x), l));
}
__device__ __forceinline__ float rlc(float4 v, int comp, int l) {
  float x = (comp == 0) ? v.x : (comp == 1) ? v.y : (comp == 2) ? v.z : v.w;
  return rl(x, l);
}

// prep: packed-float4 weight layouts.
// WT4[h][e/4][c][u] (u=e%4): lane c loads float4 covering 4 consecutive e.
// VT4[h][c/4][e][u] (u=c%4): lane e loads float4 covering 4 consecutive c.
__global__ __launch_bounds__(256) void prep_kernel(
    const float* __restrict__ Wq, const float* __restrict__ Wk,
    const float* __restrict__ Wvd, const float* __restrict__ Wvu,
    float* __restrict__ WT4q, float* __restrict__ WT4k, float* __restrict__ WT4v,
    float* __restrict__ VT4) {
  int i = blockIdx.x * 256 + threadIdx.x;
  if (i < NH * DE * DH) {
    int c = i & 63;
    int e = (i >> 6) & 511;
    int h = i >> 15;
    int src = (h * DH + c) * DE + e;
    int w4i = ((h * 128 + (e >> 2)) * 64 + c) * 4 + (e & 3);
    WT4q[w4i] = Wq[src];
    WT4k[w4i] = Wk[src];
    WT4v[w4i] = Wvd[src];
    int v4i = ((h * 16 + (c >> 2)) * 512 + e) * 4 + (c & 3);
    VT4[v4i] = Wvu[(h * DE + e) * DH + c];
  }
}

// qkv0: x -> cur copy + q/kT/v for head 0.
// x slice held distributed in registers per wave; readlane broadcasts.
__global__ __launch_bounds__(NT) void qkv0_kernel(
    const float* __restrict__ x,
    const float4* __restrict__ Wq4, const float4* __restrict__ Wk4,
    const float4* __restrict__ Wv4, float* __restrict__ cur,
    float* __restrict__ q, float* __restrict__ kT, float* __restrict__ v) {
  __shared__ float qP[NW][3][NQ][DH];
  int tid = threadIdx.x, lane = tid & 63, wv = tid >> 6;
  int j0 = blockIdx.x * NQ;

  float4 xv = ((const float4*)(x + (size_t)j0 * DE))[tid];
  ((float4*)(cur + (size_t)j0 * DE))[tid] = xv;

  int e0 = wv * 64;
  // lane l holds x[j0 + (l>>4)][e0 + (l&15)*4 .. +3]
  float4 xreg =
      *(const float4*)&x[(size_t)(j0 + (lane >> 4)) * DE + e0 + (lane & 15) * 4];

  float aq[NQ] = {0, 0, 0, 0}, ak[NQ] = {0, 0, 0, 0}, av[NQ] = {0, 0, 0, 0};
#pragma unroll
  for (int i4 = 0; i4 < 16; i4++) {
    int widx = (wv * 16 + i4) * 64 + lane;
    float4 wq4 = Wq4[widx];
    float4 wk4 = Wk4[widx];
    float4 wv4 = Wv4[widx];
#pragma unroll
    for (int r = 0; r < NQ; r++) {
      const int src = r * 16 + i4;
      float x0 = rlc(xreg, 0, src), x1 = rlc(xreg, 1, src);
      float x2 = rlc(xreg, 2, src), x3 = rlc(xreg, 3, src);
      aq[r] += x0 * wq4.x + x1 * wq4.y + x2 * wq4.z + x3 * wq4.w;
      ak[r] += x0 * wk4.x + x1 * wk4.y + x2 * wk4.z + x3 * wk4.w;
      av[r] += x0 * wv4.x + x1 * wv4.y + x2 * wv4.z + x3 * wv4.w;
    }
  }
#pragma unroll
  for (int r = 0; r < NQ; r++) {
    qP[wv][0][r][lane] = aq[r];
    qP[wv][1][r][lane] = ak[r];
    qP[wv][2][r][lane] = av[r];
  }
  __syncthreads();
  for (int i = tid; i < 3 * NQ * DH; i += NT) {
    int o = i >> 8;
    int rem = i & 255;
    int r = rem >> 6, c = rem & 63;
    float s = 0;
#pragma unroll
    for (int w = 0; w < NW; w++) s += qP[w][o][r][c];
    if (o == 0) q[(size_t)(j0 + r) * DH + c] = s;
    else if (o == 1) kT[(size_t)c * SQ + (j0 + r)] = s;
    else v[(size_t)(j0 + r) * DH + c] = s;
  }
}

// fused: attn(head h) [+ qkv(head h+1)]
// flags bit0: last head -> out = cur/8 ; bit1: compute next-head qkv
__global__ __launch_bounds__(NT) void fused_kernel(
    float* __restrict__ cur,
    const float* __restrict__ q, const float* __restrict__ kT,
    const float* __restrict__ v, const float4* __restrict__ VT4h,
    const float4* __restrict__ Wq4n, const float4* __restrict__ Wk4n,
    const float4* __restrict__ Wv4n,
    float* __restrict__ qn, float* __restrict__ kTn, float* __restrict__ vn,
    float* __restrict__ out, int flags) {
  __shared__ float sL[NQ][W2];
  __shared__ float pL[NW][NQ][DH];
  __shared__ float dL[NQ][DH];
  __shared__ float yL[NQ][DE];
  __shared__ float qP[NW][3][NQ][DH];

  int tid = threadIdx.x, lane = tid & 63, wv = tid >> 6;
  int j0 = blockIdx.x * NQ;

  // P1: scores. q rows (4x64 = 1KB) loaded distributed from GLOBAL:
  // lane l holds q[j0 + (l>>4)][(l&15)*4 .. +3]; readlane broadcasts.
  // Branch is WAVE-UNIFORM (wv < 5): all 64 lanes of participating waves are
  // active, so qreg is defined in every lane readlane may source (the R0 bug
  // was a divergent goff<UW guard letting the qreg load sink into a region
  // where wave 4 ran with exec={0..2}).
  if (wv < 5) {
    float4 qreg = ((const float4*)(q + (size_t)j0 * DH))[lane];  // all lanes
    int goff = wv * 64 + lane;   // 0..319; goff >= UW lanes compute discarded
    int g = j0 - CW + goff;
    bool valid = (g >= 0 && g < SQ);
    int gc = valid ? g : 0;
    float acc[NQ] = {0, 0, 0, 0};
#pragma unroll
    for (int d8 = 0; d8 < 8; d8++) {
      float kc[8];
#pragma unroll
      for (int u = 0; u < 8; u++) kc[u] = kT[(size_t)(d8 * 8 + u) * SQ + gc];
#pragma unroll
      for (int r = 0; r < NQ; r++) {
#pragma unroll
        for (int u = 0; u < 8; u++) {
          const int d = d8 * 8 + u;
          const int src = r * 16 + (d >> 2);
          acc[r] += rlc(qreg, d & 3, src) * kc[u];
        }
      }
    }
#pragma unroll
    for (int r = 0; r < NQ; r++) {
      int p = goff - r;
      if (p >= 0 && p < W2) sL[r][p] = valid ? acc[r] * 0.125f : -INFINITY;
    }
  }
  __syncthreads();

  // P2: softmax, wave per row
  if (wv < NQ) {
    int r = wv;
    float m = -INFINITY;
#pragma unroll
    for (int t = 0; t < 4; t++) m = fmaxf(m, sL[r][lane + 64 * t]);
#pragma unroll
    for (int off = 32; off; off >>= 1) m = fmaxf(m, __shfl_xor(m, off));
    float ex[4], ss = 0;
#pragma unroll
    for (int t = 0; t < 4; t++) {
      ex[t] = __expf(sL[r][lane + 64 * t] - m);
      ss += ex[t];
    }
#pragma unroll
    for (int off = 32; off; off >>= 1) ss += __shfl_xor(ss, off);
    float inv = 1.0f / ss;
#pragma unroll
    for (int t = 0; t < 4; t++) sL[r][lane + 64 * t] = ex[t] * inv;
  }
  __syncthreads();

  // P3: PV. The 132 wave-uniform softmax weights are staged distributed
  // (3 ds_read per lane, straight-line all-active code) then readlane-
  // broadcast. wst is defined in every lane via the select (masked -> 0).
  {
    float dacc[NQ] = {0, 0, 0, 0};
    int gbeg = 33 * wv;
    // stage: lane l = (r_l, i_l); chunk c covers window slot i = c*16 + i_l
    float wst[3];
    {
      int r_l = lane >> 4, i_l = lane & 15;
#pragma unroll
      for (int c = 0; c < 3; c++) {
        int idx = gbeg - r_l + c * 16 + i_l;  // = p for (r_l, i)
        bool ok = ((unsigned)idx < W2);
        float val = sL[r_l][idx & 255];
        wst[c] = ok ? val : 0.0f;
      }
    }
#pragma unroll
    for (int ch = 0; ch < 3; ch++) {
      const int cnt = (ch < 2) ? 16 : 1;  // 33 positions per wave
      float vcv[16];
#pragma unroll
      for (int i = 0; i < cnt; i++) {
        int goff = gbeg + ch * 16 + i;
        int g = j0 - CW + goff;
        int gc = g < 0 ? 0 : (g >= SQ ? SQ - 1 : g);
        vcv[i] = v[(size_t)gc * DH + lane];
      }
#pragma unroll
      for (int i = 0; i < cnt; i++) {
#pragma unroll
        for (int r = 0; r < NQ; r++) {
          float ws = rl(wst[ch], r * 16 + i);  // sL[r][goff-r] or 0
          dacc[r] += ws * vcv[i];
        }
      }
    }
#pragma unroll
    for (int r = 0; r < NQ; r++) pL[wv][r][lane] = dacc[r];
  }
  __syncthreads();
  if (tid < NQ * DH) {
    int r = tid >> 6, c = tid & 63;
    float s = 0;
#pragma unroll
    for (int w = 0; w < NW; w++) s += pL[w][r][c];
    dL[r][c] = s;
  }
  __syncthreads();

  // P5: upproj. dL (4x64 = 1KB) read distributed: ONE ds_read_b128 per wave,
  // then readlane broadcasts; thread owns e = tid. Straight-line all-active.
  float c8[8];
  {
    int e = tid;
    float cr[NQ];
#pragma unroll
    for (int r = 0; r < NQ; r++) cr[r] = cur[(size_t)(j0 + r) * DE + e];
    if (wv < NQ) {
      size_t jrow = (size_t)(j0 + wv) * DE;
#pragma unroll
      for (int t = 0; t < 8; t++) c8[t] = cur[jrow + lane + 64 * t];
    }
    float4 dreg = ((const float4*)dL)[lane];  // lane l: dL[l>>4][(l&15)*4..]
    float acc[NQ] = {0, 0, 0, 0};
#pragma unroll
    for (int c4 = 0; c4 < 16; c4++) {
      float4 wc4 = VT4h[c4 * 512 + e];
#pragma unroll
      for (int r = 0; r < NQ; r++) {
        const int src = r * 16 + c4;
        acc[r] += rlc(dreg, 0, src) * wc4.x + rlc(dreg, 1, src) * wc4.y +
                  rlc(dreg, 2, src) * wc4.z + rlc(dreg, 3, src) * wc4.w;
      }
    }
#pragma unroll
    for (int r = 0; r < NQ; r++) yL[r][e] = cr[r] + acc[r];
  }
  __syncthreads();

  // P6: renorm + residual; wave per row
  if (wv < NQ) {
    int r = wv;
    size_t jrow = (size_t)(j0 + r) * DE;
    float s = 0;
#pragma unroll
    for (int t = 0; t < 8; t++) s += yL[r][lane + 64 * t];
#pragma unroll
    for (int off = 32; off; off >>= 1) s += __shfl_xor(s, off);
    float inv_m1 = 512.0f / s;
    float y2[8], s2 = 0, s2q = 0;
#pragma unroll
    for (int t = 0; t < 8; t++) {
      y2[t] = yL[r][lane + 64 * t] * inv_m1;
      s2 += y2[t];
      s2q += y2[t] * y2[t];
    }
#pragma unroll
    for (int off = 32; off; off >>= 1) {
      s2 += __shfl_xor(s2, off);
      s2q += __shfl_xor(s2q, off);
    }
    float m2 = s2 * (1.0f / 512.0f);
    float var = (s2q - 512.0f * m2 * m2) * (1.0f / 511.0f);
    float isd = 1.0f / sqrtf(var);
#pragma unroll
    for (int t = 0; t < 8; t++) {
      int e = lane + 64 * t;
      float o = (y2[t] - m2) * isd + m2;
      float nc = c8[t] + o;
      cur[jrow + e] = nc;
      yL[r][e] = nc;
      if (flags & 1) out[jrow + e] = nc * (1.0f / NH);
    }
  }
  __syncthreads();

  // P7: next-head qkv. y slice (4 rows x 64 e = 1KB) read distributed:
  // ONE ds_read_b128 per wave; readlane broadcasts into 12 FMAs per step.
  // Guard (flags & 2) is wave-uniform -> all lanes active inside.
  if (flags & 2) {
    int e0 = wv * 64;
    // lane l holds yL[l>>4][e0 + (l&15)*4 .. +3]
    float4 yreg = *(const float4*)&yL[lane >> 4][e0 + (lane & 15) * 4];
    float aq[NQ] = {0, 0, 0, 0}, ak[NQ] = {0, 0, 0, 0}, av[NQ] = {0, 0, 0, 0};
#pragma unroll
    for (int i4 = 0; i4 < 16; i4++) {
      int widx = (wv * 16 + i4) * 64 + lane;
      float4 wq4 = Wq4n[widx];
      float4 wk4 = Wk4n[widx];
      float4 wv4 = Wv4n[widx];
#pragma unroll
      for (int r = 0; r < NQ; r++) {
        const int src = r * 16 + i4;
        float x0 = rlc(yreg, 0, src), x1 = rlc(yreg, 1, src);
        float x2 = rlc(yreg, 2, src), x3 = rlc(yreg, 3, src);
        aq[r] += x0 * wq4.x + x1 * wq4.y + x2 * wq4.z + x3 * wq4.w;
        ak[r] += x0 * wk4.x + x1 * wk4.y + x2 * wk4.z + x3 * wk4.w;
        av[r] += x0 * wv4.x + x1 * wv4.y + x2 * wv4.z + x3 * wv4.w;
      }
    }
#pragma unroll
    for (int r = 0; r < NQ; r++) {
      qP[wv][0][r][lane] = aq[r];
      qP[wv][1][r][lane] = ak[r];
      qP[wv][2][r][lane] = av[r];
    }
    __syncthreads();
    for (int i = tid; i < 3 * NQ * DH; i += NT) {
      int o = i >> 8;
      int rem = i & 255;
      int r = rem >> 6, c = rem & 63;
      float s = 0;
#pragma unroll
      for (int w = 0; w < NW; w++) s += qP[w][o][r][c];
      if (o == 0) qn[(size_t)(j0 + r) * DH + c] = s;
      else if (o == 1) kTn[(size_t)c * SQ + (j0 + r)] = s;
      else vn[(size_t)(j0 + r) * DH + c] = s;
    }
  }
}

extern "C" void kernel_launch(void* const* d_in, const int* in_sizes, int n_in,
                              void* d_out, int out_size, void* d_ws, size_t ws_size,
                              hipStream_t stream) {
  const float* x   = (const float*)d_in[0];
  const float* Wq  = (const float*)d_in[1];
  const float* Wk  = (const float*)d_in[2];
  const float* Wvd = (const float*)d_in[3];
  const float* Wvu = (const float*)d_in[4];
  float* out = (float*)d_out;

  float* ws  = (float*)d_ws;
  float* cur = ws;                    // SQ*DE
  float* qA  = cur + SQ * DE;         // SQ*DH each; k in kT layout [DH][SQ]
  float* kA  = qA + SQ * DH;
  float* vA  = kA + SQ * DH;
  float* qB  = vA + SQ * DH;
  float* kB  = qB + SQ * DH;
  float* vB  = kB + SQ * DH;
  float* WTq = vB + SQ * DH;          // NH*DE*DH each (packed float4 layout)
  float* WTk = WTq + NH * DE * DH;
  float* WTv = WTk + NH * DE * DH;
  float* VT  = WTv + NH * DE * DH;    // NH*DH*DE (packed float4 layout)

  prep_kernel<<<NH * DE * DH / 256, 256, 0, stream>>>(Wq, Wk, Wvd, Wvu,
                                                      WTq, WTk, WTv, VT);
  qkv0_kernel<<<SQ / NQ, NT, 0, stream>>>(
      x, (const float4*)WTq, (const float4*)WTk, (const float4*)WTv,
      cur, qA, kA, vA);

  for (int h = 0; h < NH; h++) {
    const float* qi = (h & 1) ? qB : qA;
    const float* ki = (h & 1) ? kB : kA;
    const float* vi = (h & 1) ? vB : vA;
    float* qo = (h & 1) ? qA : qB;
    float* ko = (h & 1) ? kA : kB;
    float* vo = (h & 1) ? vA : vB;
    const size_t won = (size_t)(h + 1 < NH ? h + 1 : 0) * DE * DH / 4;
    int flags = (h == NH - 1 ? 1 : 0) | (h < NH - 1 ? 2 : 0);
    fused_kernel<<<SQ / NQ, NT, 0, stream>>>(
        cur, qi, ki, vi, (const float4*)VT + (size_t)h * DH * DE / 4,
        (const float4*)WTq + won, (const float4*)WTk + won,
        (const float4*)WTv + won, qo, ko, vo, out, flags);
  }
}

// Round 3
// 315.032 us; speedup vs baseline: 1.1657x; 1.1657x over previous
//
#include <hip/hip_runtime.h>
#include <math.h>

#define SQ 2048      // seq len
#define DE 512       // d_embedding
#define DH 64        // d_head
#define CW 128       // half-window
#define W2 256       // window width
#define NH 8         // heads
#define NQ 4         // queries per block
#define UW (W2 + NQ - 1)  // union window width = 259
#define NT 512       // threads per block
#define NW 8         // waves per block

// XCD-chunk swizzle (bijective for 512 blocks, 8 XCDs): dispatch d -> XCD d%8
// (round-robin), so give XCD k the contiguous row band [k*256, (k+1)*256).
// Window reads (+-128 rows) then stay ~75% within the same XCD's L2, and the
// previous kernel's writers of those rows sit on the same XCD too.
__device__ __forceinline__ int swz_block(int b) {
  return ((b & 7) << 6) | (b >> 3);
}

// prep: packed-float4 weight layouts.
// WT4[h][e/4][c][u] (u=e%4): lane c loads float4 covering 4 consecutive e.
// VT4[h][c/4][e][u] (u=c%4): lane e loads float4 covering 4 consecutive c.
__global__ __launch_bounds__(256) void prep_kernel(
    const float* __restrict__ Wq, const float* __restrict__ Wk,
    const float* __restrict__ Wvd, const float* __restrict__ Wvu,
    float* __restrict__ WT4q, float* __restrict__ WT4k, float* __restrict__ WT4v,
    float* __restrict__ VT4) {
  int i = blockIdx.x * 256 + threadIdx.x;
  if (i < NH * DE * DH) {
    int c = i & 63;
    int e = (i >> 6) & 511;
    int h = i >> 15;
    int src = (h * DH + c) * DE + e;
    int w4i = ((h * 128 + (e >> 2)) * 64 + c) * 4 + (e & 3);
    WT4q[w4i] = Wq[src];
    WT4k[w4i] = Wk[src];
    WT4v[w4i] = Wvd[src];
    int v4i = ((h * 16 + (c >> 2)) * 512 + e) * 4 + (c & 3);
    VT4[v4i] = Wvu[(h * DE + e) * DH + c];
  }
}

// qkv0: x -> cur copy + q/kT/v for head 0 (float4 weight loads)
__global__ __launch_bounds__(NT) void qkv0_kernel(
    const float* __restrict__ x,
    const float4* __restrict__ Wq4, const float4* __restrict__ Wk4,
    const float4* __restrict__ Wv4, float* __restrict__ cur,
    float* __restrict__ q, float* __restrict__ kT, float* __restrict__ v) {
  __shared__ float xL[NQ][DE];
  __shared__ float qP[NW][3][NQ][DH];
  int tid = threadIdx.x, lane = tid & 63, wv = tid >> 6;
  int j0 = swz_block(blockIdx.x) * NQ;

  float4 xv = ((const float4*)(x + (size_t)j0 * DE))[tid];
  ((float4*)xL)[tid] = xv;
  ((float4*)(cur + (size_t)j0 * DE))[tid] = xv;
  __syncthreads();

  float aq[NQ] = {0, 0, 0, 0}, ak[NQ] = {0, 0, 0, 0}, av[NQ] = {0, 0, 0, 0};
  int e0 = wv * 64;
#pragma unroll
  for (int i4 = 0; i4 < 16; i4++) {
    int widx = (wv * 16 + i4) * 64 + lane;
    float4 wq4 = Wq4[widx];
    float4 wk4 = Wk4[widx];
    float4 wv4 = Wv4[widx];
#pragma unroll
    for (int r = 0; r < NQ; r++) {
      float4 xr = ((const float4*)&xL[r][e0])[i4];
      aq[r] += xr.x * wq4.x + xr.y * wq4.y + xr.z * wq4.z + xr.w * wq4.w;
      ak[r] += xr.x * wk4.x + xr.y * wk4.y + xr.z * wk4.z + xr.w * wk4.w;
      av[r] += xr.x * wv4.x + xr.y * wv4.y + xr.z * wv4.z + xr.w * wv4.w;
    }
  }
#pragma unroll
  for (int r = 0; r < NQ; r++) {
    qP[wv][0][r][lane] = aq[r];
    qP[wv][1][r][lane] = ak[r];
    qP[wv][2][r][lane] = av[r];
  }
  __syncthreads();
  for (int i = tid; i < 3 * NQ * DH; i += NT) {
    int o = i >> 8;
    int rem = i & 255;
    int r = rem >> 6, c = rem & 63;
    float s = 0;
#pragma unroll
    for (int w = 0; w < NW; w++) s += qP[w][o][r][c];
    if (o == 0) q[(size_t)(j0 + r) * DH + c] = s;
    else if (o == 1) kT[(size_t)c * SQ + (j0 + r)] = s;
    else v[(size_t)(j0 + r) * DH + c] = s;
  }
}

// fused: attn(head h) [+ qkv(head h+1)]
// flags bit0: last head -> out = cur/8 ; bit1: compute next-head qkv
__global__ __launch_bounds__(NT) void fused_kernel(
    float* __restrict__ cur,
    const float* __restrict__ q, const float* __restrict__ kT,
    const float* __restrict__ v, const float4* __restrict__ VT4h,
    const float4* __restrict__ Wq4n, const float4* __restrict__ Wk4n,
    const float4* __restrict__ Wv4n,
    float* __restrict__ qn, float* __restrict__ kTn, float* __restrict__ vn,
    float* __restrict__ out, int flags) {
  // LDS aliasing: qP (24KB, live only in P7, first write after the post-P6
  // barrier) overlays sL+pL (12KB, dead after the dL-reduce barrier).
  // 45KB -> 33KB per block.
  __shared__ union SMem {
    struct { float sL[NQ][W2]; float pL[NW][NQ][DH]; } a;
    float qP[NW][3][NQ][DH];
  } sm;
  __shared__ float qL[NQ][DH];
  __shared__ float dL[NQ][DH];
  __shared__ float yL[NQ][DE];

  int tid = threadIdx.x, lane = tid & 63, wv = tid >> 6;
  int j0 = swz_block(blockIdx.x) * NQ;

  // P0: stage q rows
  if (tid < NQ * DH) ((float*)qL)[tid] = q[(size_t)j0 * DH + tid];
  __syncthreads();

  // P1: scores; 8 kT loads in flight per chunk
  {
    int goff = wv * 64 + lane;
    if (goff < UW) {
      int g = j0 - CW + goff;
      bool valid = (g >= 0 && g < SQ);
      int gc = valid ? g : 0;
      float acc[NQ] = {0, 0, 0, 0};
#pragma unroll
      for (int d8 = 0; d8 < 8; d8++) {
        float kc[8];
#pragma unroll
        for (int u = 0; u < 8; u++) kc[u] = kT[(size_t)(d8 * 8 + u) * SQ + gc];
#pragma unroll
        for (int r = 0; r < NQ; r++) {
          float4 q0 = ((const float4*)qL[r])[2 * d8];
          float4 q1 = ((const float4*)qL[r])[2 * d8 + 1];
          acc[r] += q0.x * kc[0] + q0.y * kc[1] + q0.z * kc[2] + q0.w * kc[3] +
                    q1.x * kc[4] + q1.y * kc[5] + q1.z * kc[6] + q1.w * kc[7];
        }
      }
#pragma unroll
      for (int r = 0; r < NQ; r++) {
        int p = goff - r;
        if (p >= 0 && p < W2) sm.a.sL[r][p] = valid ? acc[r] * 0.125f : -INFINITY;
      }
    }
  }
  __syncthreads();

  // v-prefetch (chunk 0 of P3): v is a kernel input, independent of softmax.
  // Issue the 16 loads now so their latency hides under P2 + its barrier.
  int gbeg = 33 * wv;
  float vpf[16];
#pragma unroll
  for (int i = 0; i < 16; i++) {
    int goff = gbeg + i;
    int g = j0 - CW + goff;
    int gc = g < 0 ? 0 : (g >= SQ ? SQ - 1 : g);
    vpf[i] = v[(size_t)gc * DH + lane];
  }

  // P2: softmax, wave per row
  if (wv < NQ) {
    int r = wv;
    float m = -INFINITY;
#pragma unroll
    for (int t = 0; t < 4; t++) m = fmaxf(m, sm.a.sL[r][lane + 64 * t]);
#pragma unroll
    for (int off = 32; off; off >>= 1) m = fmaxf(m, __shfl_xor(m, off));
    float ex[4], ss = 0;
#pragma unroll
    for (int t = 0; t < 4; t++) {
      ex[t] = __expf(sm.a.sL[r][lane + 64 * t] - m);
      ss += ex[t];
    }
#pragma unroll
    for (int off = 32; off; off >>= 1) ss += __shfl_xor(ss, off);
    float inv = 1.0f / ss;
#pragma unroll
    for (int t = 0; t < 4; t++) sm.a.sL[r][lane + 64 * t] = ex[t] * inv;
  }
  __syncthreads();

  // P3: PV. Chunk 0 uses prefetched v; chunks 1-2 (17 values) load inline.
  {
    float dacc[NQ] = {0, 0, 0, 0};
#pragma unroll
    for (int i = 0; i < 16; i++) {
      int goff = gbeg + i;
#pragma unroll
      for (int r = 0; r < NQ; r++) {
        int p = goff - r;
        float w = (goff < UW && p >= 0 && p < W2) ? sm.a.sL[r][p & 255] : 0.0f;
        dacc[r] += w * vpf[i];
      }
    }
    {
      float vcv[17];
#pragma unroll
      for (int i = 0; i < 17; i++) {
        int goff = gbeg + 16 + i;
        int g = j0 - CW + goff;
        int gc = g < 0 ? 0 : (g >= SQ ? SQ - 1 : g);
        vcv[i] = v[(size_t)gc * DH + lane];
      }
#pragma unroll
      for (int i = 0; i < 17; i++) {
        int goff = gbeg + 16 + i;
        bool act = goff < UW;
#pragma unroll
        for (int r = 0; r < NQ; r++) {
          int p = goff - r;
          float w = (act && p >= 0 && p < W2) ? sm.a.sL[r][p & 255] : 0.0f;
          dacc[r] += w * vcv[i];
        }
      }
    }
#pragma unroll
    for (int r = 0; r < NQ; r++) sm.a.pL[wv][r][lane] = dacc[r];
  }
  __syncthreads();
  if (tid < NQ * DH) {
    int r = tid >> 6, c = tid & 63;
    float s = 0;
#pragma unroll
    for (int w = 0; w < NW; w++) s += sm.a.pL[w][r][c];
    dL[r][c] = s;
  }
  __syncthreads();

  // P5: upproj with float4 VT loads; thread owns e = tid
  float c8[8];
  {
    int e = tid;
    float cr[NQ];
#pragma unroll
    for (int r = 0; r < NQ; r++) cr[r] = cur[(size_t)(j0 + r) * DE + e];
    if (wv < NQ) {
      size_t jrow = (size_t)(j0 + wv) * DE;
#pragma unroll
      for (int t = 0; t < 8; t++) c8[t] = cur[jrow + lane + 64 * t];
    }
    float acc[NQ] = {0, 0, 0, 0};
#pragma unroll
    for (int c4 = 0; c4 < 16; c4++) {
      float4 wc4 = VT4h[c4 * 512 + e];
#pragma unroll
      for (int r = 0; r < NQ; r++) {
        float4 df = ((const float4*)dL[r])[c4];
        acc[r] += df.x * wc4.x + df.y * wc4.y + df.z * wc4.z + df.w * wc4.w;
      }
    }
#pragma unroll
    for (int r = 0; r < NQ; r++) yL[r][e] = cr[r] + acc[r];
  }
  __syncthreads();

  // P6: renorm + residual; wave per row
  if (wv < NQ) {
    int r = wv;
    size_t jrow = (size_t)(j0 + r) * DE;
    float s = 0;
#pragma unroll
    for (int t = 0; t < 8; t++) s += yL[r][lane + 64 * t];
#pragma unroll
    for (int off = 32; off; off >>= 1) s += __shfl_xor(s, off);
    float inv_m1 = 512.0f / s;
    float y2[8], s2 = 0, s2q = 0;
#pragma unroll
    for (int t = 0; t < 8; t++) {
      y2[t] = yL[r][lane + 64 * t] * inv_m1;
      s2 += y2[t];
      s2q += y2[t] * y2[t];
    }
#pragma unroll
    for (int off = 32; off; off >>= 1) {
      s2 += __shfl_xor(s2, off);
      s2q += __shfl_xor(s2q, off);
    }
    float m2 = s2 * (1.0f / 512.0f);
    float var = (s2q - 512.0f * m2 * m2) * (1.0f / 511.0f);
    float isd = 1.0f / sqrtf(var);
#pragma unroll
    for (int t = 0; t < 8; t++) {
      int e = lane + 64 * t;
      float o = (y2[t] - m2) * isd + m2;
      float nc = c8[t] + o;
      cur[jrow + e] = nc;
      yL[r][e] = nc;
      if (flags & 1) out[jrow + e] = nc * (1.0f / NH);
    }
  }
  __syncthreads();

  // P7: next-head qkv with float4 weight loads; wave e-slice.
  // (qP aliases sL/pL -- all their reads are ordered before this barrier.)
  if (flags & 2) {
    float aq[NQ] = {0, 0, 0, 0}, ak[NQ] = {0, 0, 0, 0}, av[NQ] = {0, 0, 0, 0};
    int e0 = wv * 64;
#pragma unroll
    for (int i4 = 0; i4 < 16; i4++) {
      int widx = (wv * 16 + i4) * 64 + lane;
      float4 wq4 = Wq4n[widx];
      float4 wk4 = Wk4n[widx];
      float4 wv4 = Wv4n[widx];
#pragma unroll
      for (int r = 0; r < NQ; r++) {
        float4 xr = ((const float4*)&yL[r][e0])[i4];
        aq[r] += xr.x * wq4.x + xr.y * wq4.y + xr.z * wq4.z + xr.w * wq4.w;
        ak[r] += xr.x * wk4.x + xr.y * wk4.y + xr.z * wk4.z + xr.w * wk4.w;
        av[r] += xr.x * wv4.x + xr.y * wv4.y + xr.z * wv4.z + xr.w * wv4.w;
      }
    }
#pragma unroll
    for (int r = 0; r < NQ; r++) {
      sm.qP[wv][0][r][lane] = aq[r];
      sm.qP[wv][1][r][lane] = ak[r];
      sm.qP[wv][2][r][lane] = av[r];
    }
    __syncthreads();
    for (int i = tid; i < 3 * NQ * DH; i += NT) {
      int o = i >> 8;
      int rem = i & 255;
      int r = rem >> 6, c = rem & 63;
      float s = 0;
#pragma unroll
      for (int w = 0; w < NW; w++) s += sm.qP[w][o][r][c];
      if (o == 0) qn[(size_t)(j0 + r) * DH + c] = s;
      else if (o == 1) kTn[(size_t)c * SQ + (j0 + r)] = s;
      else vn[(size_t)(j0 + r) * DH + c] = s;
    }
  }
}

extern "C" void kernel_launch(void* const* d_in, const int* in_sizes, int n_in,
                              void* d_out, int out_size, void* d_ws, size_t ws_size,
                              hipStream_t stream) {
  const float* x   = (const float*)d_in[0];
  const float* Wq  = (const float*)d_in[1];
  const float* Wk  = (const float*)d_in[2];
  const float* Wvd = (const float*)d_in[3];
  const float* Wvu = (const float*)d_in[4];
  float* out = (float*)d_out;

  float* ws  = (float*)d_ws;
  float* cur = ws;                    // SQ*DE
  float* qA  = cur + SQ * DE;         // SQ*DH each; k in kT layout [DH][SQ]
  float* kA  = qA + SQ * DH;
  float* vA  = kA + SQ * DH;
  float* qB  = vA + SQ * DH;
  float* kB  = qB + SQ * DH;
  float* vB  = kB + SQ * DH;
  float* WTq = vB + SQ * DH;          // NH*DE*DH each (packed float4 layout)
  float* WTk = WTq + NH * DE * DH;
  float* WTv = WTk + NH * DE * DH;
  float* VT  = WTv + NH * DE * DH;    // NH*DH*DE (packed float4 layout)

  prep_kernel<<<NH * DE * DH / 256, 256, 0, stream>>>(Wq, Wk, Wvd, Wvu,
                                                      WTq, WTk, WTv, VT);
  qkv0_kernel<<<SQ / NQ, NT, 0, stream>>>(
      x, (const float4*)WTq, (const float4*)WTk, (const float4*)WTv,
      cur, qA, kA, vA);

  for (int h = 0; h < NH; h++) {
    const float* qi = (h & 1) ? qB : qA;
    const float* ki = (h & 1) ? kB : kA;
    const float* vi = (h & 1) ? vB : vA;
    float* qo = (h & 1) ? qA : qB;
    float* ko = (h & 1) ? kA : kB;
    float* vo = (h & 1) ? vA : vB;
    const size_t won = (size_t)(h + 1 < NH ? h + 1 : 0) * DE * DH / 4;
    int flags = (h == NH - 1 ? 1 : 0) | (h < NH - 1 ? 2 : 0);
    fused_kernel<<<SQ / NQ, NT, 0, stream>>>(
        cur, qi, ki, vi, (const float4*)VT + (size_t)h * DH * DE / 4,
        (const float4*)WTq + won, (const float4*)WTk + won,
        (const float4*)WTv + won, qo, ko, vo, out, flags);
  }
}